// Round 20
// baseline (475.832 us; speedup 1.0000x reference)
//
#include <hip/hip_runtime.h>
#include <math.h>

typedef unsigned short u16;
typedef __attribute__((ext_vector_type(8))) short bf16x8;
typedef __attribute__((ext_vector_type(4))) float f32x4;

#define BSZ 4
#define TLEN 2048
#define DDIM 1024
#define NH 16
#define HDIM 64
#define NKOPS 4
#define RDIM 48
#define HR 768     // NH*RDIM
#define HHD 1024   // NH*HDIM
#define NALL 4096  // HHD + NKOPS*HR
#define LNEPS 1e-5f
#define GSPLIT 16
#define SST 52     // solver LDS row stride (208 B, 16B-aligned)

#define AS1 __attribute__((address_space(1)))
#define AS3 __attribute__((address_space(3)))

static __device__ __forceinline__ void gload16(const u16* g, u16* l) {
    __builtin_amdgcn_global_load_lds((const AS1 unsigned int*)g, (AS3 unsigned int*)l, 16, 0, 0);
}

static __device__ __forceinline__ int clamp_pl(int p) {
    if (p < 1) p = 1;
    if (p > TLEN - 1) p = TLEN - 1;
    return p;
}

static __device__ __forceinline__ u16 f2bf(float x) {
    unsigned u = __float_as_uint(x);
    return (u16)((u + 0x7FFFu + ((u >> 16) & 1u)) >> 16);
}
static __device__ __forceinline__ float bf2f(u16 h) {
    return __uint_as_float(((unsigned)h) << 16);
}

// 48-elem dot of two 16B-aligned LDS rows via 12+12 ds_read_b128
static __device__ __forceinline__ float dot48(const float* __restrict__ a,
                                              const float* __restrict__ b) {
    float s0 = 0.f, s1 = 0.f, s2 = 0.f, s3 = 0.f;
#pragma unroll
    for (int m = 0; m < 12; ++m) {
        float4 av = *(const float4*)(a + m * 4);
        float4 bv = *(const float4*)(b + m * 4);
        s0 += av.x * bv.x; s1 += av.y * bv.y;
        s2 += av.z * bv.z; s3 += av.w * bv.w;
    }
    return (s0 + s1) + (s2 + s3);
}

// register-tiled 3x3 block of a 48x48 row.row matmul
static __device__ __forceinline__ void mm48_3x3(const float* __restrict__ Lb,
                                                const float* __restrict__ Rb,
                                                int i0, int j0, float acc[3][3]) {
#pragma unroll
    for (int r = 0; r < 3; ++r)
#pragma unroll
        for (int c = 0; c < 3; ++c) acc[r][c] = 0.f;
#pragma unroll 4
    for (int m = 0; m < 12; ++m) {
        float4 a0 = *(const float4*)(Lb + (i0 + 0) * SST + m * 4);
        float4 a1 = *(const float4*)(Lb + (i0 + 1) * SST + m * 4);
        float4 a2 = *(const float4*)(Lb + (i0 + 2) * SST + m * 4);
        float4 b0 = *(const float4*)(Rb + (j0 + 0) * SST + m * 4);
        float4 b1 = *(const float4*)(Rb + (j0 + 1) * SST + m * 4);
        float4 b2 = *(const float4*)(Rb + (j0 + 2) * SST + m * 4);
        acc[0][0] += a0.x * b0.x + a0.y * b0.y + a0.z * b0.z + a0.w * b0.w;
        acc[0][1] += a0.x * b1.x + a0.y * b1.y + a0.z * b1.z + a0.w * b1.w;
        acc[0][2] += a0.x * b2.x + a0.y * b2.y + a0.z * b2.z + a0.w * b2.w;
        acc[1][0] += a1.x * b0.x + a1.y * b0.y + a1.z * b0.z + a1.w * b0.w;
        acc[1][1] += a1.x * b1.x + a1.y * b1.y + a1.z * b1.z + a1.w * b1.w;
        acc[1][2] += a1.x * b2.x + a1.y * b2.y + a1.z * b2.z + a1.w * b2.w;
        acc[2][0] += a2.x * b0.x + a2.y * b0.y + a2.z * b0.z + a2.w * b0.w;
        acc[2][1] += a2.x * b1.x + a2.y * b1.y + a2.z * b1.z + a2.w * b1.w;
        acc[2][2] += a2.x * b2.x + a2.y * b2.y + a2.z * b2.z + a2.w * b2.w;
    }
}

#define WB() __builtin_amdgcn_wave_barrier()

// ---------------- LayerNorm -> bf16 hi/lo split ----------------
__global__ __launch_bounds__(256) void ln_kernel(const float* __restrict__ hs,
                                                 const float* __restrict__ g,
                                                 const float* __restrict__ b,
                                                 u16* __restrict__ nh,
                                                 u16* __restrict__ nl)
{
    int row = blockIdx.x;
    int tid = threadIdx.x;
    const float* x = hs + (size_t)row * DDIM;
    float4 v = ((const float4*)x)[tid];
    float s  = v.x + v.y + v.z + v.w;
    float ss = v.x*v.x + v.y*v.y + v.z*v.z + v.w*v.w;
    for (int off = 32; off > 0; off >>= 1) {
        s  += __shfl_down(s, off);
        ss += __shfl_down(ss, off);
    }
    __shared__ float rs[4], rss[4], st[2];
    int wid = tid >> 6, lane = tid & 63;
    if (lane == 0) { rs[wid] = s; rss[wid] = ss; }
    __syncthreads();
    if (tid == 0) {
        float S  = rs[0] + rs[1] + rs[2] + rs[3];
        float SS = rss[0] + rss[1] + rss[2] + rss[3];
        float mu = S / (float)DDIM;
        float var = SS / (float)DDIM - mu * mu;
        st[0] = mu;
        st[1] = rsqrtf(var + LNEPS);
    }
    __syncthreads();
    float mu = st[0], rstd = st[1];
    float4 gv = ((const float4*)g)[tid];
    float4 bv = ((const float4*)b)[tid];
    float o[4];
    o[0] = (v.x - mu) * rstd * gv.x + bv.x;
    o[1] = (v.y - mu) * rstd * gv.y + bv.y;
    o[2] = (v.z - mu) * rstd * gv.z + bv.z;
    o[3] = (v.w - mu) * rstd * gv.w + bv.w;
    u16 h[4], l[4];
#pragma unroll
    for (int i = 0; i < 4; ++i) {
        h[i] = f2bf(o[i]);
        l[i] = f2bf(o[i] - bf2f(h[i]));
    }
    uint2 ph, pl2;
    ph.x = (unsigned)h[0] | ((unsigned)h[1] << 16);
    ph.y = (unsigned)h[2] | ((unsigned)h[3] << 16);
    pl2.x = (unsigned)l[0] | ((unsigned)l[1] << 16);
    pl2.y = (unsigned)l[2] | ((unsigned)l[3] << 16);
    *(uint2*)(nh + (size_t)row * DDIM + tid * 4) = ph;
    *(uint2*)(nl + (size_t)row * DDIM + tid * 4) = pl2;
}

// ---------------- transpose + bf16 hi/lo convert: in[R][C] f32 -> out[C][R] ----------------
__global__ __launch_bounds__(256) void transcvt(const float* __restrict__ in,
                                                u16* __restrict__ oh,
                                                u16* __restrict__ ol,
                                                int R, int C)
{
    __shared__ float t[32][33];
    int bx = blockIdx.x, by = blockIdx.y;
    int tx = threadIdx.x & 31, ty = threadIdx.x >> 5;
#pragma unroll
    for (int j = 0; j < 4; ++j)
        t[ty + j * 8][tx] = in[(size_t)(by * 32 + ty + j * 8) * C + bx * 32 + tx];
    __syncthreads();
#pragma unroll
    for (int j = 0; j < 4; ++j) {
        float v = t[tx][ty + j * 8];
        u16 h = f2bf(v);
        size_t o = (size_t)(bx * 32 + ty + j * 8) * R + by * 32 + tx;
        oh[o] = h;
        ol[o] = f2bf(v - bf2f(h));
    }
}

// ---------------- batched WK transpose: 4 ops in one launch (z = k) ----------------
__global__ __launch_bounds__(256) void transcvt_wk(const float* __restrict__ WK,
                                                   u16* __restrict__ oh,
                                                   u16* __restrict__ ol)
{
    __shared__ float t[32][33];
    int bx = blockIdx.x, by = blockIdx.y, k = blockIdx.z;
    const float* in = WK + (size_t)k * DDIM * HR;
    u16* ohk = oh + (size_t)k * (HR * DDIM);
    u16* olk = ol + (size_t)k * (HR * DDIM);
    int tx = threadIdx.x & 31, ty = threadIdx.x >> 5;
#pragma unroll
    for (int j = 0; j < 4; ++j)
        t[ty + j * 8][tx] = in[(size_t)(by * 32 + ty + j * 8) * HR + bx * 32 + tx];
    __syncthreads();
#pragma unroll
    for (int j = 0; j < 4; ++j) {
        float v = t[tx][ty + j * 8];
        u16 h = f2bf(v);
        size_t o = (size_t)(bx * 32 + ty + j * 8) * DDIM + by * 32 + tx;
        ohk[o] = h;
        olk[o] = f2bf(v - bf2f(h));
    }
}

// ---------------- split-bf16 MFMA GEMM (NT): C[z] = A[z] @ Bt[z]^T ----------------
template<int OMODE>
__global__ __launch_bounds__(256) void gemm_mfma(
    const u16* __restrict__ Ah, const u16* __restrict__ Al, long sAz,
    const u16* __restrict__ Bth, const u16* __restrict__ Btl, long sBz,
    float* __restrict__ C, u16* __restrict__ Oh, u16* __restrict__ Ol, long sCz,
    int M, int N, int K,
    const int* __restrict__ pl_ptr, const float* __restrict__ gate_ptr)
{
    int z = blockIdx.z;
    int m0 = blockIdx.y * 128, n0 = blockIdx.x * 128;
    if (pl_ptr) {
        int p = clamp_pl(pl_ptr[0]);
        if (m0 >= (p < M ? p : M)) return;
    }
    Ah  += (size_t)z * sAz;  Al  += (size_t)z * sAz;
    Bth += (size_t)z * sBz;  Btl += (size_t)z * sBz;

    __shared__ u16 As[2][128][32];
    __shared__ u16 Bs[2][128][32];

    int tid = threadIdx.x;
    int wid = tid >> 6, ln = tid & 63;
    int wm = (wid >> 1) * 64, wn = (wid & 1) * 64;
    int r16 = ln & 15, kg = ln >> 4;

    int rb = wid * 32;
    int lr = ln >> 2;
    int sl = ln & 3;
    int koff = (sl ^ (((rb + lr) >> 1) & 3)) * 8;

    const u16* gA0h = Ah  + (size_t)(m0 + rb + lr) * K + koff;
    const u16* gA1h = gA0h + (size_t)16 * K;
    const u16* gA0l = Al  + (size_t)(m0 + rb + lr) * K + koff;
    const u16* gA1l = gA0l + (size_t)16 * K;
    const u16* gB0h = Bth + (size_t)(n0 + rb + lr) * K + koff;
    const u16* gB1h = gB0h + (size_t)16 * K;
    const u16* gB0l = Btl + (size_t)(n0 + rb + lr) * K + koff;
    const u16* gB1l = gB0l + (size_t)16 * K;

    u16* lA0h = &As[0][rb][0];      u16* lA1h = &As[0][rb + 16][0];
    u16* lA0l = &As[1][rb][0];      u16* lA1l = &As[1][rb + 16][0];
    u16* lB0h = &Bs[0][rb][0];      u16* lB1h = &Bs[0][rb + 16][0];
    u16* lB0l = &Bs[1][rb][0];      u16* lB1l = &Bs[1][rb + 16][0];

    f32x4 acc[4][4];
#pragma unroll
    for (int mt = 0; mt < 4; ++mt)
#pragma unroll
        for (int nt = 0; nt < 4; ++nt)
            acc[mt][nt] = (f32x4){0.f, 0.f, 0.f, 0.f};

    for (int k0 = 0; k0 < K; k0 += 32) {
        __syncthreads();
        gload16(gA0h, lA0h);  gload16(gA1h, lA1h);
        gload16(gA0l, lA0l);  gload16(gA1l, lA1l);
        gload16(gB0h, lB0h);  gload16(gB1h, lB1h);
        gload16(gB0l, lB0l);  gload16(gB1l, lB1l);
        gA0h += 32; gA1h += 32; gA0l += 32; gA1l += 32;
        gB0h += 32; gB1h += 32; gB0l += 32; gB1l += 32;
        __syncthreads();

        bf16x8 bhf[4], blf[4];
#pragma unroll
        for (int nt = 0; nt < 4; ++nt) {
            int r = wn + nt * 16 + r16;
            int s = (kg ^ ((r >> 1) & 3)) * 8;
            bhf[nt] = *(const bf16x8*)&Bs[0][r][s];
            blf[nt] = *(const bf16x8*)&Bs[1][r][s];
        }
#pragma unroll
        for (int mt = 0; mt < 4; ++mt) {
            int r = wm + mt * 16 + r16;
            int s = (kg ^ ((r >> 1) & 3)) * 8;
            bf16x8 ah = *(const bf16x8*)&As[0][r][s];
            bf16x8 al = *(const bf16x8*)&As[1][r][s];
#pragma unroll
            for (int nt = 0; nt < 4; ++nt) {
                acc[mt][nt] = __builtin_amdgcn_mfma_f32_16x16x32_bf16(ah, bhf[nt], acc[mt][nt], 0, 0, 0);
                acc[mt][nt] = __builtin_amdgcn_mfma_f32_16x16x32_bf16(ah, blf[nt], acc[mt][nt], 0, 0, 0);
                acc[mt][nt] = __builtin_amdgcn_mfma_f32_16x16x32_bf16(al, bhf[nt], acc[mt][nt], 0, 0, 0);
            }
        }
    }

    int orow0 = m0 + wm + kg * 4;
    int ocol0 = n0 + wn + r16;
    if (OMODE == 0) {
        float scale = 1.0f;
        if (gate_ptr) scale = 1.0f / (1.0f + expf(-gate_ptr[0]));
        float* Cz = C + (size_t)z * sCz;
#pragma unroll
        for (int mt = 0; mt < 4; ++mt)
#pragma unroll
            for (int nt = 0; nt < 4; ++nt)
#pragma unroll
                for (int j = 0; j < 4; ++j)
                    Cz[(size_t)(orow0 + mt * 16 + j) * N + ocol0 + nt * 16] = acc[mt][nt][j] * scale;
    } else {
        u16* Ohz = Oh + (size_t)z * sCz;
        u16* Olz = Ol + (size_t)z * sCz;
#pragma unroll
        for (int mt = 0; mt < 4; ++mt)
#pragma unroll
            for (int nt = 0; nt < 4; ++nt)
#pragma unroll
                for (int j = 0; j < 4; ++j) {
                    float v = acc[mt][nt][j];
                    u16 h = f2bf(v);
                    size_t o = (size_t)(orow0 + mt * 16 + j) * N + ocol0 + nt * 16;
                    Ohz[o] = h;
                    Olz[o] = f2bf(v - bf2f(h));
                }
    }
}

// ---------------- Gram (fallback): 16-way interleaved time-split partials ----------------
__global__ __launch_bounds__(256) void gram_kernel(const float* __restrict__ Kp,
                                                   const float* __restrict__ Vp,
                                                   float* __restrict__ Gpart,
                                                   float* __restrict__ Mpart,
                                                   float* __restrict__ Cpart,
                                                   const int* __restrict__ pl_ptr)
{
    int h = blockIdx.x, b = blockIdx.y, sp = blockIdx.z;
    int pl = clamp_pl(pl_ptr[0]);
    __shared__ float pks[65][48];
    __shared__ float pvs[64][64];
    int tid = threadIdx.x;
    int tx = tid & 15, ty = tid >> 4;
    float gacc[3][3] = {}, macc[3][3] = {}, cacc[4][3] = {};
    const float* Kbase = Kp + (size_t)b * TLEN * HR + h * RDIM;
    const float* Vbase = Vp + (size_t)b * TLEN * HHD + h * HDIM;
    const float4 z4 = make_float4(0.f, 0.f, 0.f, 0.f);

    for (int c0 = sp * 64; c0 < pl; c0 += GSPLIT * 64) {
        for (int idx = tid; idx < 65 * 12; idx += 256) {
            int rr = idx / 12, c4 = idx % 12;
            int tg = c0 + rr;
            *(float4*)&pks[rr][c4 * 4] =
                (tg < pl) ? *(const float4*)&Kbase[(size_t)tg * HR + c4 * 4] : z4;
        }
        for (int idx = tid; idx < 64 * 16; idx += 256) {
            int rr = idx >> 4, c4 = idx & 15;
            int tg = c0 + rr;
            *(float4*)&pvs[rr][c4 * 4] =
                (tg < pl) ? *(const float4*)&Vbase[(size_t)tg * HHD + c4 * 4] : z4;
        }
        __syncthreads();
        float cura[3], curb[3];
#pragma unroll
        for (int i = 0; i < 3; ++i) {
            cura[i] = pks[0][tx * 3 + i];
            curb[i] = pks[0][ty * 3 + i];
        }
#pragma unroll 2
        for (int l = 0; l < 64; ++l) {
            float nxta[3], nxtb[3];
#pragma unroll
            for (int i = 0; i < 3; ++i) {
                nxta[i] = pks[l + 1][tx * 3 + i];
                nxtb[i] = pks[l + 1][ty * 3 + i];
            }
            float4 v4 = *(const float4*)&pvs[l][ty * 4];
            float vv[4] = { v4.x, v4.y, v4.z, v4.w };
#pragma unroll
            for (int i = 0; i < 3; ++i)
#pragma unroll
                for (int j = 0; j < 3; ++j) {
                    gacc[i][j] += cura[i] * curb[j];
                    macc[i][j] += nxta[i] * curb[j];
                }
#pragma unroll
            for (int j = 0; j < 4; ++j)
#pragma unroll
                for (int i = 0; i < 3; ++i)
                    cacc[j][i] += vv[j] * cura[i];
#pragma unroll
            for (int i = 0; i < 3; ++i) { cura[i] = nxta[i]; curb[i] = nxtb[i]; }
        }
        __syncthreads();
    }
    size_t pbase = (size_t)sp * (BSZ * NH) + b * NH + h;
    float* Gp = Gpart + pbase * 2304;
    float* Mp = Mpart + pbase * 2304;
    float* Cp = Cpart + pbase * 3072;
#pragma unroll
    for (int i = 0; i < 3; ++i)
#pragma unroll
        for (int j = 0; j < 3; ++j) {
            Gp[(tx * 3 + i) * 48 + (ty * 3 + j)] = gacc[i][j];
            Mp[(tx * 3 + i) * 48 + (ty * 3 + j)] = macc[i][j];
        }
#pragma unroll
    for (int j = 0; j < 4; ++j)
#pragma unroll
        for (int i = 0; i < 3; ++i)
            Cp[(ty * 4 + j) * 48 + (tx * 3 + i)] = cacc[j][i];
}

// ---------------- Gram (batched): z = k*spk+sp, reads Call (stride NALL) ----------------
__global__ __launch_bounds__(256) void gram_all(const float* __restrict__ Call,
                                                float* __restrict__ Gpart,
                                                float* __restrict__ Mpart,
                                                float* __restrict__ Cpart,
                                                int spk,
                                                const int* __restrict__ pl_ptr)
{
    int h = blockIdx.x, b = blockIdx.y, zz = blockIdx.z;
    int k = zz / spk, sp = zz - k * spk;
    int pl = clamp_pl(pl_ptr[0]);
    __shared__ float pks[65][48];
    __shared__ float pvs[64][64];
    int tid = threadIdx.x;
    int tx = tid & 15, ty = tid >> 4;
    float gacc[3][3] = {}, macc[3][3] = {}, cacc[4][3] = {};
    const float* Kbase = Call + (size_t)b * TLEN * NALL + (HHD + k * HR) + h * RDIM;
    const float* Vbase = Call + (size_t)b * TLEN * NALL + h * HDIM;
    const float4 z4 = make_float4(0.f, 0.f, 0.f, 0.f);

    for (int c0 = sp * 64; c0 < pl; c0 += spk * 64) {
        for (int idx = tid; idx < 65 * 12; idx += 256) {
            int rr = idx / 12, c4 = idx % 12;
            int tg = c0 + rr;
            *(float4*)&pks[rr][c4 * 4] =
                (tg < pl) ? *(const float4*)&Kbase[(size_t)tg * NALL + c4 * 4] : z4;
        }
        for (int idx = tid; idx < 64 * 16; idx += 256) {
            int rr = idx >> 4, c4 = idx & 15;
            int tg = c0 + rr;
            *(float4*)&pvs[rr][c4 * 4] =
                (tg < pl) ? *(const float4*)&Vbase[(size_t)tg * NALL + c4 * 4] : z4;
        }
        __syncthreads();
        float cura[3], curb[3];
#pragma unroll
        for (int i = 0; i < 3; ++i) {
            cura[i] = pks[0][tx * 3 + i];
            curb[i] = pks[0][ty * 3 + i];
        }
#pragma unroll 2
        for (int l = 0; l < 64; ++l) {
            float nxta[3], nxtb[3];
#pragma unroll
            for (int i = 0; i < 3; ++i) {
                nxta[i] = pks[l + 1][tx * 3 + i];
                nxtb[i] = pks[l + 1][ty * 3 + i];
            }
            float4 v4 = *(const float4*)&pvs[l][ty * 4];
            float vv[4] = { v4.x, v4.y, v4.z, v4.w };
#pragma unroll
            for (int i = 0; i < 3; ++i)
#pragma unroll
                for (int j = 0; j < 3; ++j) {
                    gacc[i][j] += cura[i] * curb[j];
                    macc[i][j] += nxta[i] * curb[j];
                }
#pragma unroll
            for (int j = 0; j < 4; ++j)
#pragma unroll
                for (int i = 0; i < 3; ++i)
                    cacc[j][i] += vv[j] * cura[i];
#pragma unroll
            for (int i = 0; i < 3; ++i) { cura[i] = nxta[i]; curb[i] = nxtb[i]; }
        }
        __syncthreads();
    }
    size_t pbase = (size_t)zz * (BSZ * NH) + b * NH + h;   // region zz = k*spk+sp
    float* Gp = Gpart + pbase * 2304;
    float* Mp = Mpart + pbase * 2304;
    float* Cp = Cpart + pbase * 3072;
#pragma unroll
    for (int i = 0; i < 3; ++i)
#pragma unroll
        for (int j = 0; j < 3; ++j) {
            Gp[(tx * 3 + i) * 48 + (ty * 3 + j)] = gacc[i][j];
            Mp[(tx * 3 + i) * 48 + (ty * 3 + j)] = macc[i][j];
        }
#pragma unroll
    for (int j = 0; j < 4; ++j)
#pragma unroll
        for (int i = 0; i < 3; ++i)
            Cp[(ty * 4 + j) * 48 + (tx * 3 + i)] = cacc[j][i];
}

// fallback reduce: GSPLIT partials -> per-k slot
__global__ __launch_bounds__(256) void gram_reduce(const float* __restrict__ Gpart,
                                                   const float* __restrict__ Mpart,
                                                   const float* __restrict__ Cpart,
                                                   float* __restrict__ Gb,
                                                   float* __restrict__ Mb,
                                                   float* __restrict__ Cb,
                                                   int k)
{
    int p = blockIdx.x;               // b*NH+h
    size_t ob = ((size_t)k * (BSZ * NH) + p);
    for (int idx = threadIdx.x; idx < 2304; idx += 256) {
        float sg = 0.f, sm = 0.f;
#pragma unroll
        for (int sp = 0; sp < GSPLIT; ++sp) {
            size_t pb = ((size_t)sp * (BSZ * NH) + p);
            sg += Gpart[pb * 2304 + idx];
            sm += Mpart[pb * 2304 + idx];
        }
        Gb[ob * 2304 + idx] = sg;
        Mb[ob * 2304 + idx] = sm;
    }
    for (int idx = threadIdx.x; idx < 3072; idx += 256) {
        float sc = 0.f;
#pragma unroll
        for (int sp = 0; sp < GSPLIT; ++sp)
            sc += Cpart[((size_t)sp * (BSZ * NH) + p) * 3072 + idx];
        Cb[ob * 3072 + idx] = sc;
    }
}

// batched reduce: grid 256 (blk = k*64 + p), spk partial regions per k
__global__ __launch_bounds__(256) void gram_reduce_all(const float* __restrict__ Gpart,
                                                       const float* __restrict__ Mpart,
                                                       const float* __restrict__ Cpart,
                                                       float* __restrict__ Gb,
                                                       float* __restrict__ Mb,
                                                       float* __restrict__ Cb,
                                                       int spk)
{
    int blk = blockIdx.x;             // (k*64 + b*NH+h)
    int k = blk >> 6, p = blk & 63;
    size_t ob = (size_t)blk;
    for (int idx = threadIdx.x; idx < 2304; idx += 256) {
        float sg = 0.f, sm = 0.f;
        for (int sp = 0; sp < spk; ++sp) {
            size_t pb = ((size_t)(k * spk + sp) * (BSZ * NH) + p);
            sg += Gpart[pb * 2304 + idx];
            sm += Mpart[pb * 2304 + idx];
        }
        Gb[ob * 2304 + idx] = sg;
        Mb[ob * 2304 + idx] = sm;
    }
    for (int idx = threadIdx.x; idx < 3072; idx += 256) {
        float sc = 0.f;
        for (int sp = 0; sp < spk; ++sp)
            sc += Cpart[((size_t)(k * spk + sp) * (BSZ * NH) + p) * 3072 + idx];
        Cb[ob * 3072 + idx] = sc;
    }
}

// ---------------- per-(k,b,h) fused solver: F = C_v * (scl^2 * P*P*H) ----------------
__global__ __launch_bounds__(256) void solver_kernel(const float* __restrict__ Gb,
                                                     const float* __restrict__ Mb,
                                                     const float* __restrict__ Cb,
                                                     float* __restrict__ Fb,
                                                     const float* __restrict__ log_ridges,
                                                     const float* __restrict__ log_gammas)
{
    int blk = blockIdx.x;                 // (k*BSZ + b)*NH + h
    int k = blk / (BSZ * NH);
    int tid = threadIdx.x;
    int ti = tid >> 4, tj = tid & 15;
    int i0 = ti * 3, j0 = tj * 3;

    __shared__ float A [48 * SST];
    __shared__ float Hs[48 * SST];
    __shared__ float Mm[48 * SST];
    __shared__ float Pm[48 * SST];
    __shared__ float Pt[48 * SST];
    __shared__ float pvb[4][SST];

    size_t base = (size_t)blk;
    const float* Gp = Gb + base * 2304;
    const float* Mp = Mb + base * 2304;
    const float* Cp = Cb + base * 3072;
    float ridge = expf(log_ridges[k]);

    for (int idx = tid; idx < 2304; idx += 256) {
        int i = idx / 48, j = idx % 48;
        A [i * SST + j] = Gp[idx] + ((i == j) ? ridge : 0.f);
        Hs[i * SST + j] = (i == j) ? 1.f : 0.f;
        Mm[i * SST + j] = Mp[idx];
    }
    __syncthreads();

    for (int p = 0; p < 48; ++p) {
        int p4 = p >> 2;
        float pr = 1.0f / fmaxf(A[p * SST + p], 1e-30f);
        int c4a = p4 + 1;
        int nA4 = 11 - p4;
        int nb  = 3 - (p & 3);
        for (int q = tid; q < 576; q += 256) {
            int i = q / 12, c = q % 12;
            if (i == p) continue;
            float f = A[i * SST + p] * pr;
            if (c < nA4) {
                int c4 = c4a + c;
                float4 prw = *(const float4*)&A[p * SST + c4 * 4];
                float4* d = (float4*)&A[i * SST + c4 * 4];
                float4 v = *d;
                v.x -= f * prw.x; v.y -= f * prw.y;
                v.z -= f * prw.z; v.w -= f * prw.w;
                *d = v;
            } else {
                int c4 = c - nA4;
                float4 prw = *(const float4*)&Hs[p * SST + c4 * 4];
                float4* d = (float4*)&Hs[i * SST + c4 * 4];
                float4 v = *d;
                v.x -= f * prw.x; v.y -= f * prw.y;
                v.z -= f * prw.z; v.w -= f * prw.w;
                *d = v;
            }
        }
        if (nb) {
            for (int i = tid; i < 48; i += 256) {
                if (i == p) continue;
                float f = A[i * SST + p] * pr;
                for (int c = p + 1; c < 4 * c4a; ++c)
                    A[i * SST + c] -= f * A[p * SST + c];
            }
        }
        __syncthreads();
    }
    for (int idx = tid; idx < 2304; idx += 256) {
        int i = idx / 48, j = idx % 48;
        Hs[i * SST + j] /= fmaxf(A[i * SST + i], 1e-30f);
    }
    __syncthreads();
    for (int idx = tid; idx < 2304; idx += 256) {
        int i = idx / 48, j = idx % 48;
        A[j * SST + i] = Mm[i * SST + j];
    }
    __syncthreads();
    {
        float acc[3][3];
        mm48_3x3(Hs, A, i0, j0, acc);
#pragma unroll
        for (int r = 0; r < 3; ++r)
#pragma unroll
            for (int c = 0; c < 3; ++c) {
                Pm[(i0 + r) * SST + j0 + c] = acc[r][c];
                Pt[(j0 + c) * SST + i0 + r] = acc[r][c];
            }
    }
    __syncthreads();
    {
        float acc[3][3];
        mm48_3x3(Hs, Mm, i0, j0, acc);
        __syncthreads();
#pragma unroll
        for (int r = 0; r < 3; ++r)
#pragma unroll
            for (int c = 0; c < 3; ++c)
                A[(i0 + r) * SST + j0 + c] = acc[r][c];
    }
    __syncthreads();
    {
        float acc[3][3];
        mm48_3x3(A, Pt, i0, j0, acc);
        __syncthreads();
#pragma unroll
        for (int r = 0; r < 3; ++r)
#pragma unroll
            for (int c = 0; c < 3; ++c) {
                Mm[(i0 + r) * SST + j0 + c] = acc[r][c];
                A [(j0 + c) * SST + i0 + r] = acc[r][c];
            }
    }
    __syncthreads();
    {
        float acc[3][3];
        mm48_3x3(Mm, A, i0, j0, acc);
#pragma unroll
        for (int r = 0; r < 3; ++r)
#pragma unroll
            for (int c = 0; c < 3; ++c)
                Pt[(i0 + r) * SST + j0 + c] = acc[r][c];
    }
    __syncthreads();
    for (int idx = tid; idx < 2304; idx += 256) {
        int i = idx / 48, j = idx % 48;
        A[j * SST + i] = Pt[i * SST + j];
    }
    __syncthreads();
    {
        float acc[3][3];
        mm48_3x3(Pt, A, i0, j0, acc);
        __syncthreads();
#pragma unroll
        for (int r = 0; r < 3; ++r)
#pragma unroll
            for (int c = 0; c < 3; ++c)
                Mm[(i0 + r) * SST + j0 + c] = acc[r][c];
    }
    __syncthreads();

    int ln = tid & 63, w = tid >> 6;
    float* pv = pvb[w];
    if (ln < 48) pv[ln] = ((float)((ln * 2654435761u) & 0xFFFF)) / 65536.0f + 0.5f;
    WB();
    float lam = 0.f;
    for (int it = 0; it < 25; ++it) {
        float z = 0.f;
        if (ln < 48) z = dot48(&Mm[ln * SST], pv);
        if (it == 24) {
            float nn = z * z;
            for (int off = 1; off < 64; off <<= 1) nn += __shfl_xor(nn, off);
            lam = sqrtf(nn);
            break;
        }
        if ((it & 1) == 1) {
            float nn = z * z;
            for (int off = 1; off < 64; off <<= 1) nn += __shfl_xor(nn, off);
            z *= rsqrtf(fmaxf(nn, 1e-30f));
        }
        WB();
        if (ln < 48) pv[ln] = z;
        WB();
    }
    float sigma = sqrtf(sqrtf(sqrtf(fmaxf(lam, 0.f))));
    float gamma = expf(log_gammas[k]);
    float scl = fminf(gamma, 1.f) / fmaxf(fmaxf(sigma, 1e-8f), 1.f);
    float s2 = scl * scl;

    {
        float acc[3][3];
        mm48_3x3(Pm, Hs, i0, j0, acc);
        __syncthreads();
#pragma unroll
        for (int r = 0; r < 3; ++r)
#pragma unroll
            for (int c = 0; c < 3; ++c)
                A[(j0 + c) * SST + i0 + r] = acc[r][c];
    }
    __syncthreads();
    {
        float acc[3][3];
        mm48_3x3(Pm, A, i0, j0, acc);
        __syncthreads();
#pragma unroll
        for (int r = 0; r < 3; ++r)
#pragma unroll
            for (int c = 0; c < 3; ++c)
                Pt[(j0 + c) * SST + i0 + r] = s2 * acc[r][c];
    }
    __syncthreads();
    for (int idx = tid; idx < 3072; idx += 256) {
        int row = idx / 48, col = idx % 48;
        float v = Cp[idx];
        if (row < 48) Mm[row * SST + col] = v;
        else          A [(row - 48) * SST + col] = v;
    }
    __syncthreads();
    {
        int fi0 = ti * 4, fj0 = tj * 3;
        const float* crow0 = (fi0 < 48) ? &Mm[fi0 * SST] : &A[(fi0 - 48) * SST];
        float acc[4][3];
#pragma unroll
        for (int r = 0; r < 4; ++r)
#pragma unroll
            for (int c = 0; c < 3; ++c) acc[r][c] = 0.f;
#pragma unroll 4
        for (int m = 0; m < 12; ++m) {
            float4 a0 = *(const float4*)(crow0 + 0 * SST + m * 4);
            float4 a1 = *(const float4*)(crow0 + 1 * SST + m * 4);
            float4 a2 = *(const float4*)(crow0 + 2 * SST + m * 4);
            float4 a3 = *(const float4*)(crow0 + 3 * SST + m * 4);
            float4 b0 = *(const float4*)(&Pt[(fj0 + 0) * SST] + m * 4);
            float4 b1 = *(const float4*)(&Pt[(fj0 + 1) * SST] + m * 4);
            float4 b2 = *(const float4*)(&Pt[(fj0 + 2) * SST] + m * 4);
            acc[0][0] += a0.x*b0.x + a0.y*b0.y + a0.z*b0.z + a0.w*b0.w;
            acc[0][1] += a0.x*b1.x + a0.y*b1.y + a0.z*b1.z + a0.w*b1.w;
            acc[0][2] += a0.x*b2.x + a0.y*b2.y + a0.z*b2.z + a0.w*b2.w;
            acc[1][0] += a1.x*b0.x + a1.y*b0.y + a1.z*b0.z + a1.w*b0.w;
            acc[1][1] += a1.x*b1.x + a1.y*b1.y + a1.z*b1.z + a1.w*b1.w;
            acc[1][2] += a1.x*b2.x + a1.y*b2.y + a1.z*b2.z + a1.w*b2.w;
            acc[2][0] += a2.x*b0.x + a2.y*b0.y + a2.z*b0.z + a2.w*b0.w;
            acc[2][1] += a2.x*b1.x + a2.y*b1.y + a2.z*b1.z + a2.w*b1.w;
            acc[2][2] += a2.x*b2.x + a2.y*b2.y + a2.z*b2.z + a2.w*b2.w;
            acc[3][0] += a3.x*b0.x + a3.y*b0.y + a3.z*b0.z + a3.w*b0.w;
            acc[3][1] += a3.x*b1.x + a3.y*b1.y + a3.z*b1.z + a3.w*b1.w;
            acc[3][2] += a3.x*b2.x + a3.y*b2.y + a3.z*b2.z + a3.w*b2.w;
        }
#pragma unroll
        for (int r = 0; r < 4; ++r)
#pragma unroll
            for (int c = 0; c < 3; ++c)
                Fb[base * 3072 + (size_t)(fi0 + r) * 48 + fj0 + c] = acc[r][c];
    }
}

// ---------------- W_cmb build -> bf16 hi/lo ----------------
__global__ __launch_bounds__(256) void wcmb_kernel(const float* __restrict__ WQ,
                                                   const float* __restrict__ Fb,
                                                   const float* __restrict__ gate_alphas,
                                                   u16* __restrict__ Wh,
                                                   u16* __restrict__ Wl)
{
    int dt = blockIdx.x;
    int h = blockIdx.y, b = blockIdx.z;
    __shared__ float wq[64][49];
    __shared__ float fs[64][49];
    int tid = threadIdx.x;
    int tx = tid & 15, ty = tid >> 4;
    float acc[4][4] = {};
    for (int k = 0; k < NKOPS; ++k) {
        float gate = 1.0f / (1.0f + expf(-gate_alphas[k]));
        for (int idx = tid; idx < 64 * 48; idx += 256) {
            int rr = idx / 48, cc = idx % 48;
            wq[rr][cc] = WQ[((size_t)k * DDIM + dt * 64 + rr) * HR + h * RDIM + cc];
            fs[rr][cc] = gate * Fb[(((size_t)k * BSZ + b) * NH + h) * 3072 + idx];
        }
        __syncthreads();
        for (int r = 0; r < 48; ++r) {
            float a[4], bb[4];
#pragma unroll
            for (int i = 0; i < 4; ++i) { a[i] = wq[tx * 4 + i][r]; bb[i] = fs[ty * 4 + i][r]; }
#pragma unroll
            for (int i = 0; i < 4; ++i)
#pragma unroll
                for (int j = 0; j < 4; ++j)
                    acc[i][j] += a[i] * bb[j];
        }
        __syncthreads();
    }
#pragma unroll
    for (int i = 0; i < 4; ++i)
#pragma unroll
        for (int j = 0; j < 4; ++j) {
            size_t o = ((size_t)b * DDIM + dt * 64 + tx * 4 + i) * HHD + h * HDIM + ty * 4 + j;
            float v = acc[i][j];
            u16 hh = f2bf(v);
            Wh[o] = hh;
            Wl[o] = f2bf(v - bf2f(hh));
        }
}

// ---------------- host launch ----------------
extern "C" void kernel_launch(void* const* d_in, const int* in_sizes, int n_in,
                              void* d_out, int out_size, void* d_ws, size_t ws_size,
                              hipStream_t stream)
{
    const float* hs          = (const float*)d_in[0];
    const float* WK          = (const float*)d_in[1];
    const float* WQ          = (const float*)d_in[2];
    const float* WV          = (const float*)d_in[3];
    const float* WO          = (const float*)d_in[4];
    const float* ln_g        = (const float*)d_in[5];
    const float* ln_b        = (const float*)d_in[6];
    const float* gate_alphas = (const float*)d_in[7];
    const float* gate_alpha  = (const float*)d_in[8];
    const float* log_ridges  = (const float*)d_in[9];
    const float* log_gammas  = (const float*)d_in[10];
    const int*   pl_ptr      = (const int*)d_in[11];
    float* out = (float*)d_out;
    float* wsf = (float*)d_ws;

    // gram partials in d_out (dead before final GEMM overwrites all of d_out)
    float* GpartO = out;                     // 16*64*2304 = 2,359,296
    float* MpartO = out + 2359296;           // 2,359,296
    float* CpartO = out + 4718592;           // 3,145,728 (end 7,864,320 < 8,388,608)

    const size_t BIG_NEED  = (size_t)(12582912 + 33554432) * 4;                       // 184,549,376 B
    const size_t BIG2_NEED = (size_t)(12582912 + 33554432 + 2*9437184 + 12582912) * 4; // 310,378,496 B

    if (ws_size >= BIG_NEED) {
        // ===== batched path: one KV GEMM (N=4096), batched grams/reduce =====
        u16* n_hi    = (u16*)(wsf + 0);
        u16* n_lo    = (u16*)(wsf + 4194304);
        u16* Wall_h  = (u16*)(wsf + 8388608);      // [4096][1024] bf16 hi
        u16* Wall_l  = (u16*)(wsf + 10485760);
        u16* WVt_h   = Wall_h;
        u16* WVt_l   = Wall_l;
        u16* WKt_ah  = Wall_h + (size_t)HHD * DDIM;
        u16* WKt_al  = Wall_l + (size_t)HHD * DDIM;
        float* Call  = wsf + 12582912;             // [4][2048][4096] f32
        // aliases inside Call (disjoint lifetimes, stream-ordered):
        float* Gb    = Call;                       // [0,        589,824)
        float* Mb    = Call + 589824;
        float* Cb    = Call + 1179648;             // end 1,966,080
        u16* WOt_h   = (u16*)(Call + 2097152);
        u16* WOt_l   = (u16*)(Call + 2621440);
        float* Fb    = Call + 3145728;             // 786,432
        u16* Wcmb_h  = (u16*)(Call + 4194304);     // 2,097,152 f32 each
        u16* Wcmb_l  = (u16*)(Call + 6291456);
        u16* Wfint_h = (u16*)(Call + 8388608);
        u16* Wfint_l = (u16*)(Call + 10485760);    // end 12,582,912 < 33.5M

        // tier-1 partials beyond Call (64 regions) if ws allows
        bool big2 = (ws_size >= BIG2_NEED);
        float* Gpart = big2 ? (wsf + 46137344)            : GpartO;
        float* Mpart = big2 ? (wsf + 46137344 + 9437184)  : MpartO;
        float* Cpart = big2 ? (wsf + 46137344 + 18874368) : CpartO;
        int spk = big2 ? 16 : 4;

        ln_kernel<<<BSZ * TLEN, 256, 0, stream>>>(hs, ln_g, ln_b, n_hi, n_lo);
        transcvt<<<dim3(HHD / 32, DDIM / 32), 256, 0, stream>>>(WV, WVt_h, WVt_l, DDIM, HHD);
        transcvt_wk<<<dim3(HR / 32, DDIM / 32, NKOPS), 256, 0, stream>>>(WK, WKt_ah, WKt_al);

        // Call = normed_prefix @ [WV | WK0..3]
        gemm_mfma<0><<<dim3(NALL / 128, TLEN / 128, BSZ), 256, 0, stream>>>(
            n_hi, n_lo, (long)TLEN * DDIM, Wall_h, Wall_l, 0,
            Call, nullptr, nullptr, (long)TLEN * NALL,
            TLEN, NALL, DDIM, pl_ptr, nullptr);

        gram_all<<<dim3(NH, BSZ, NKOPS * spk), 256, 0, stream>>>(
            Call, Gpart, Mpart, Cpart, spk, pl_ptr);
        gram_reduce_all<<<NKOPS * BSZ * NH, 256, 0, stream>>>(
            Gpart, Mpart, Cpart, Gb, Mb, Cb, spk);

        transcvt<<<dim3(DDIM / 32, HHD / 32), 256, 0, stream>>>(WO, WOt_h, WOt_l, HHD, DDIM);

        solver_kernel<<<NKOPS * BSZ * NH, 256, 0, stream>>>(Gb, Mb, Cb, Fb, log_ridges, log_gammas);
        wcmb_kernel<<<dim3(DDIM / 64, NH, BSZ), 256, 0, stream>>>(WQ, Fb, gate_alphas, Wcmb_h, Wcmb_l);

        gemm_mfma<1><<<dim3(DDIM / 128, DDIM / 128, BSZ), 256, 0, stream>>>(
            WOt_h, WOt_l, 0, Wcmb_h, Wcmb_l, (long)DDIM * HHD,
            nullptr, Wfint_h, Wfint_l, (long)DDIM * DDIM,
            DDIM, DDIM, HHD, nullptr, nullptr);

        gemm_mfma<0><<<dim3(DDIM / 128, TLEN / 128, BSZ), 256, 0, stream>>>(
            n_hi, n_lo, (long)TLEN * DDIM, Wfint_h, Wfint_l, (long)DDIM * DDIM,
            out, nullptr, nullptr, (long)TLEN * DDIM,
            TLEN, DDIM, DDIM, nullptr, gate_alpha);
        return;
    }

    // ===== fallback path: r17 structure =====
    u16* n_hi    = (u16*)(wsf + 0);
    u16* n_lo    = (u16*)(wsf + 4194304);
    u16* WVt_h   = (u16*)(wsf + 8388608);
    u16* WVt_l   = (u16*)(wsf + 8912896);
    u16* WKt_ah  = (u16*)(wsf + 9437184);
    u16* WKt_al  = (u16*)(wsf + 11010048);
    float* Vp    = wsf + 12582912;
    float* Kp    = wsf + 20971520;
    float* Gb    = wsf + 27262976;
    float* Mb    = wsf + 27852800;
    float* Cb    = wsf + 28442624;
    u16* Wcmb_h  = (u16*)Vp;
    u16* Wcmb_l  = (u16*)(Vp + 2097152);
    u16* Wfint_h = (u16*)(Vp + 4194304);
    u16* Wfint_l = (u16*)(Vp + 6291456);
    u16* WOt_h   = (u16*)Kp;
    u16* WOt_l   = (u16*)(Kp + 524288);
    float* Fb    = Kp + 1048576;

    ln_kernel<<<BSZ * TLEN, 256, 0, stream>>>(hs, ln_g, ln_b, n_hi, n_lo);
    transcvt_wk<<<dim3(HR / 32, DDIM / 32, NKOPS), 256, 0, stream>>>(WK, WKt_ah, WKt_al);
    transcvt<<<dim3(HHD / 32, DDIM / 32), 256, 0, stream>>>(WV, WVt_h, WVt_l, DDIM, HHD);

    gemm_mfma<0><<<dim3(HHD / 128, TLEN / 128, BSZ), 256, 0, stream>>>(
        n_hi, n_lo, (long)TLEN * DDIM, WVt_h, WVt_l, 0,
        Vp, nullptr, nullptr, (long)TLEN * HHD,
        TLEN, HHD, DDIM, pl_ptr, nullptr);

    for (int k = 0; k < NKOPS; ++k) {
        gemm_mfma<0><<<dim3(HR / 128, TLEN / 128, BSZ), 256, 0, stream>>>(
            n_hi, n_lo, (long)TLEN * DDIM,
            WKt_ah + (size_t)k * (HR * DDIM), WKt_al + (size_t)k * (HR * DDIM), 0,
            Kp, nullptr, nullptr, (long)TLEN * HR,
            TLEN, HR, DDIM, pl_ptr, nullptr);
        gram_kernel<<<dim3(NH, BSZ, GSPLIT), 256, 0, stream>>>(Kp, Vp, GpartO, MpartO, CpartO, pl_ptr);
        gram_reduce<<<BSZ * NH, 256, 0, stream>>>(GpartO, MpartO, CpartO, Gb, Mb, Cb, k);
    }

    transcvt<<<dim3(DDIM / 32, HHD / 32), 256, 0, stream>>>(WO, WOt_h, WOt_l, HHD, DDIM);

    solver_kernel<<<NKOPS * BSZ * NH, 256, 0, stream>>>(Gb, Mb, Cb, Fb, log_ridges, log_gammas);
    wcmb_kernel<<<dim3(DDIM / 64, NH, BSZ), 256, 0, stream>>>(WQ, Fb, gate_alphas, Wcmb_h, Wcmb_l);

    gemm_mfma<1><<<dim3(DDIM / 128, DDIM / 128, BSZ), 256, 0, stream>>>(
        WOt_h, WOt_l, 0, Wcmb_h, Wcmb_l, (long)DDIM * HHD,
        nullptr, Wfint_h, Wfint_l, (long)DDIM * DDIM,
        DDIM, DDIM, HHD, nullptr, nullptr);

    gemm_mfma<0><<<dim3(DDIM / 128, TLEN / 128, BSZ), 256, 0, stream>>>(
        n_hi, n_lo, (long)TLEN * DDIM, Wfint_h, Wfint_l, (long)DDIM * DDIM,
        out, nullptr, nullptr, (long)TLEN * DDIM,
        TLEN, DDIM, DDIM, nullptr, gate_alpha);
}

// Round 21
// 452.715 us; speedup vs baseline: 1.0511x; 1.0511x over previous
//
#include <hip/hip_runtime.h>
#include <math.h>

typedef unsigned short u16;
typedef __attribute__((ext_vector_type(8))) short bf16x8;
typedef __attribute__((ext_vector_type(4))) float f32x4;

#define BSZ 4
#define TLEN 2048
#define DDIM 1024
#define NH 16
#define HDIM 64
#define NKOPS 4
#define RDIM 48
#define HR 768     // NH*RDIM
#define HHD 1024   // NH*HDIM
#define NALL 4096  // HHD + NKOPS*HR
#define LNEPS 1e-5f
#define GSPLIT 16
#define SST 52     // solver LDS row stride (208 B, 16B-aligned)

#define AS1 __attribute__((address_space(1)))
#define AS3 __attribute__((address_space(3)))

static __device__ __forceinline__ void gload16(const u16* g, u16* l) {
    __builtin_amdgcn_global_load_lds((const AS1 unsigned int*)g, (AS3 unsigned int*)l, 16, 0, 0);
}

static __device__ __forceinline__ int clamp_pl(int p) {
    if (p < 1) p = 1;
    if (p > TLEN - 1) p = TLEN - 1;
    return p;
}

static __device__ __forceinline__ u16 f2bf(float x) {
    unsigned u = __float_as_uint(x);
    return (u16)((u + 0x7FFFu + ((u >> 16) & 1u)) >> 16);
}
static __device__ __forceinline__ float bf2f(u16 h) {
    return __uint_as_float(((unsigned)h) << 16);
}

// 48-elem dot of two 16B-aligned LDS rows via 12+12 ds_read_b128
static __device__ __forceinline__ float dot48(const float* __restrict__ a,
                                              const float* __restrict__ b) {
    float s0 = 0.f, s1 = 0.f, s2 = 0.f, s3 = 0.f;
#pragma unroll
    for (int m = 0; m < 12; ++m) {
        float4 av = *(const float4*)(a + m * 4);
        float4 bv = *(const float4*)(b + m * 4);
        s0 += av.x * bv.x; s1 += av.y * bv.y;
        s2 += av.z * bv.z; s3 += av.w * bv.w;
    }
    return (s0 + s1) + (s2 + s3);
}

// register-tiled 3x3 block of a 48x48 row.row matmul
static __device__ __forceinline__ void mm48_3x3(const float* __restrict__ Lb,
                                                const float* __restrict__ Rb,
                                                int i0, int j0, float acc[3][3]) {
#pragma unroll
    for (int r = 0; r < 3; ++r)
#pragma unroll
        for (int c = 0; c < 3; ++c) acc[r][c] = 0.f;
#pragma unroll 4
    for (int m = 0; m < 12; ++m) {
        float4 a0 = *(const float4*)(Lb + (i0 + 0) * SST + m * 4);
        float4 a1 = *(const float4*)(Lb + (i0 + 1) * SST + m * 4);
        float4 a2 = *(const float4*)(Lb + (i0 + 2) * SST + m * 4);
        float4 b0 = *(const float4*)(Rb + (j0 + 0) * SST + m * 4);
        float4 b1 = *(const float4*)(Rb + (j0 + 1) * SST + m * 4);
        float4 b2 = *(const float4*)(Rb + (j0 + 2) * SST + m * 4);
        acc[0][0] += a0.x * b0.x + a0.y * b0.y + a0.z * b0.z + a0.w * b0.w;
        acc[0][1] += a0.x * b1.x + a0.y * b1.y + a0.z * b1.z + a0.w * b1.w;
        acc[0][2] += a0.x * b2.x + a0.y * b2.y + a0.z * b2.z + a0.w * b2.w;
        acc[1][0] += a1.x * b0.x + a1.y * b0.y + a1.z * b0.z + a1.w * b0.w;
        acc[1][1] += a1.x * b1.x + a1.y * b1.y + a1.z * b1.z + a1.w * b1.w;
        acc[1][2] += a1.x * b2.x + a1.y * b2.y + a1.z * b2.z + a1.w * b2.w;
        acc[2][0] += a2.x * b0.x + a2.y * b0.y + a2.z * b0.z + a2.w * b0.w;
        acc[2][1] += a2.x * b1.x + a2.y * b1.y + a2.z * b1.z + a2.w * b1.w;
        acc[2][2] += a2.x * b2.x + a2.y * b2.y + a2.z * b2.z + a2.w * b2.w;
    }
}

#define WB() __builtin_amdgcn_wave_barrier()

// ---------------- LayerNorm -> bf16 hi/lo split ----------------
__global__ __launch_bounds__(256) void ln_kernel(const float* __restrict__ hs,
                                                 const float* __restrict__ g,
                                                 const float* __restrict__ b,
                                                 u16* __restrict__ nh,
                                                 u16* __restrict__ nl)
{
    int row = blockIdx.x;
    int tid = threadIdx.x;
    const float* x = hs + (size_t)row * DDIM;
    float4 v = ((const float4*)x)[tid];
    float s  = v.x + v.y + v.z + v.w;
    float ss = v.x*v.x + v.y*v.y + v.z*v.z + v.w*v.w;
    for (int off = 32; off > 0; off >>= 1) {
        s  += __shfl_down(s, off);
        ss += __shfl_down(ss, off);
    }
    __shared__ float rs[4], rss[4], st[2];
    int wid = tid >> 6, lane = tid & 63;
    if (lane == 0) { rs[wid] = s; rss[wid] = ss; }
    __syncthreads();
    if (tid == 0) {
        float S  = rs[0] + rs[1] + rs[2] + rs[3];
        float SS = rss[0] + rss[1] + rss[2] + rss[3];
        float mu = S / (float)DDIM;
        float var = SS / (float)DDIM - mu * mu;
        st[0] = mu;
        st[1] = rsqrtf(var + LNEPS);
    }
    __syncthreads();
    float mu = st[0], rstd = st[1];
    float4 gv = ((const float4*)g)[tid];
    float4 bv = ((const float4*)b)[tid];
    float o[4];
    o[0] = (v.x - mu) * rstd * gv.x + bv.x;
    o[1] = (v.y - mu) * rstd * gv.y + bv.y;
    o[2] = (v.z - mu) * rstd * gv.z + bv.z;
    o[3] = (v.w - mu) * rstd * gv.w + bv.w;
    u16 h[4], l[4];
#pragma unroll
    for (int i = 0; i < 4; ++i) {
        h[i] = f2bf(o[i]);
        l[i] = f2bf(o[i] - bf2f(h[i]));
    }
    uint2 ph, pl2;
    ph.x = (unsigned)h[0] | ((unsigned)h[1] << 16);
    ph.y = (unsigned)h[2] | ((unsigned)h[3] << 16);
    pl2.x = (unsigned)l[0] | ((unsigned)l[1] << 16);
    pl2.y = (unsigned)l[2] | ((unsigned)l[3] << 16);
    *(uint2*)(nh + (size_t)row * DDIM + tid * 4) = ph;
    *(uint2*)(nl + (size_t)row * DDIM + tid * 4) = pl2;
}

// ---------------- transpose + bf16 hi/lo convert: in[R][C] f32 -> out[C][R] ----------------
__global__ __launch_bounds__(256) void transcvt(const float* __restrict__ in,
                                                u16* __restrict__ oh,
                                                u16* __restrict__ ol,
                                                int R, int C)
{
    __shared__ float t[32][33];
    int bx = blockIdx.x, by = blockIdx.y;
    int tx = threadIdx.x & 31, ty = threadIdx.x >> 5;
#pragma unroll
    for (int j = 0; j < 4; ++j)
        t[ty + j * 8][tx] = in[(size_t)(by * 32 + ty + j * 8) * C + bx * 32 + tx];
    __syncthreads();
#pragma unroll
    for (int j = 0; j < 4; ++j) {
        float v = t[tx][ty + j * 8];
        u16 h = f2bf(v);
        size_t o = (size_t)(bx * 32 + ty + j * 8) * R + by * 32 + tx;
        oh[o] = h;
        ol[o] = f2bf(v - bf2f(h));
    }
}

// ---------------- batched WK transpose: 4 ops in one launch (z = k) ----------------
__global__ __launch_bounds__(256) void transcvt_wk(const float* __restrict__ WK,
                                                   u16* __restrict__ oh,
                                                   u16* __restrict__ ol)
{
    __shared__ float t[32][33];
    int bx = blockIdx.x, by = blockIdx.y, k = blockIdx.z;
    const float* in = WK + (size_t)k * DDIM * HR;
    u16* ohk = oh + (size_t)k * (HR * DDIM);
    u16* olk = ol + (size_t)k * (HR * DDIM);
    int tx = threadIdx.x & 31, ty = threadIdx.x >> 5;
#pragma unroll
    for (int j = 0; j < 4; ++j)
        t[ty + j * 8][tx] = in[(size_t)(by * 32 + ty + j * 8) * HR + bx * 32 + tx];
    __syncthreads();
#pragma unroll
    for (int j = 0; j < 4; ++j) {
        float v = t[tx][ty + j * 8];
        u16 h = f2bf(v);
        size_t o = (size_t)(bx * 32 + ty + j * 8) * DDIM + by * 32 + tx;
        ohk[o] = h;
        olk[o] = f2bf(v - bf2f(h));
    }
}

// ---------------- split-bf16 MFMA GEMM (NT): C[z] = A[z] @ Bt[z]^T ----------------
// OMODE 0: f32 row-major out (optional sigmoid gate). OMODE 1: bf16 hi/lo out.
// OMODE 2: blocked KV out -> Vp2[b][h][row][64] / Kp2[b][k][h][row][48] (C=Vp2, Oh used as Kp2 base via C2).
template<int OMODE>
__global__ __launch_bounds__(256) void gemm_mfma(
    const u16* __restrict__ Ah, const u16* __restrict__ Al, long sAz,
    const u16* __restrict__ Bth, const u16* __restrict__ Btl, long sBz,
    float* __restrict__ C, float* __restrict__ C2, u16* __restrict__ Oh, u16* __restrict__ Ol, long sCz,
    int M, int N, int K,
    const int* __restrict__ pl_ptr, const float* __restrict__ gate_ptr)
{
    int z = blockIdx.z;
    int m0 = blockIdx.y * 128, n0 = blockIdx.x * 128;
    if (pl_ptr) {
        int p = clamp_pl(pl_ptr[0]);
        if (m0 >= (p < M ? p : M)) return;
    }
    Ah  += (size_t)z * sAz;  Al  += (size_t)z * sAz;
    Bth += (size_t)z * sBz;  Btl += (size_t)z * sBz;

    __shared__ u16 As[2][128][32];
    __shared__ u16 Bs[2][128][32];

    int tid = threadIdx.x;
    int wid = tid >> 6, ln = tid & 63;
    int wm = (wid >> 1) * 64, wn = (wid & 1) * 64;
    int r16 = ln & 15, kg = ln >> 4;

    int rb = wid * 32;
    int lr = ln >> 2;
    int sl = ln & 3;
    int koff = (sl ^ (((rb + lr) >> 1) & 3)) * 8;

    const u16* gA0h = Ah  + (size_t)(m0 + rb + lr) * K + koff;
    const u16* gA1h = gA0h + (size_t)16 * K;
    const u16* gA0l = Al  + (size_t)(m0 + rb + lr) * K + koff;
    const u16* gA1l = gA0l + (size_t)16 * K;
    const u16* gB0h = Bth + (size_t)(n0 + rb + lr) * K + koff;
    const u16* gB1h = gB0h + (size_t)16 * K;
    const u16* gB0l = Btl + (size_t)(n0 + rb + lr) * K + koff;
    const u16* gB1l = gB0l + (size_t)16 * K;

    u16* lA0h = &As[0][rb][0];      u16* lA1h = &As[0][rb + 16][0];
    u16* lA0l = &As[1][rb][0];      u16* lA1l = &As[1][rb + 16][0];
    u16* lB0h = &Bs[0][rb][0];      u16* lB1h = &Bs[0][rb + 16][0];
    u16* lB0l = &Bs[1][rb][0];      u16* lB1l = &Bs[1][rb + 16][0];

    f32x4 acc[4][4];
#pragma unroll
    for (int mt = 0; mt < 4; ++mt)
#pragma unroll
        for (int nt = 0; nt < 4; ++nt)
            acc[mt][nt] = (f32x4){0.f, 0.f, 0.f, 0.f};

    for (int k0 = 0; k0 < K; k0 += 32) {
        __syncthreads();
        gload16(gA0h, lA0h);  gload16(gA1h, lA1h);
        gload16(gA0l, lA0l);  gload16(gA1l, lA1l);
        gload16(gB0h, lB0h);  gload16(gB1h, lB1h);
        gload16(gB0l, lB0l);  gload16(gB1l, lB1l);
        gA0h += 32; gA1h += 32; gA0l += 32; gA1l += 32;
        gB0h += 32; gB1h += 32; gB0l += 32; gB1l += 32;
        __syncthreads();

        bf16x8 bhf[4], blf[4];
#pragma unroll
        for (int nt = 0; nt < 4; ++nt) {
            int r = wn + nt * 16 + r16;
            int s = (kg ^ ((r >> 1) & 3)) * 8;
            bhf[nt] = *(const bf16x8*)&Bs[0][r][s];
            blf[nt] = *(const bf16x8*)&Bs[1][r][s];
        }
#pragma unroll
        for (int mt = 0; mt < 4; ++mt) {
            int r = wm + mt * 16 + r16;
            int s = (kg ^ ((r >> 1) & 3)) * 8;
            bf16x8 ah = *(const bf16x8*)&As[0][r][s];
            bf16x8 al = *(const bf16x8*)&As[1][r][s];
#pragma unroll
            for (int nt = 0; nt < 4; ++nt) {
                acc[mt][nt] = __builtin_amdgcn_mfma_f32_16x16x32_bf16(ah, bhf[nt], acc[mt][nt], 0, 0, 0);
                acc[mt][nt] = __builtin_amdgcn_mfma_f32_16x16x32_bf16(ah, blf[nt], acc[mt][nt], 0, 0, 0);
                acc[mt][nt] = __builtin_amdgcn_mfma_f32_16x16x32_bf16(al, bhf[nt], acc[mt][nt], 0, 0, 0);
            }
        }
    }

    int orow0 = m0 + wm + kg * 4;
    int ocol0 = n0 + wn + r16;
    if (OMODE == 0) {
        float scale = 1.0f;
        if (gate_ptr) scale = 1.0f / (1.0f + expf(-gate_ptr[0]));
        float* Cz = C + (size_t)z * sCz;
#pragma unroll
        for (int mt = 0; mt < 4; ++mt)
#pragma unroll
            for (int nt = 0; nt < 4; ++nt)
#pragma unroll
                for (int j = 0; j < 4; ++j)
                    Cz[(size_t)(orow0 + mt * 16 + j) * N + ocol0 + nt * 16] = acc[mt][nt][j] * scale;
    } else if (OMODE == 1) {
        u16* Ohz = Oh + (size_t)z * sCz;
        u16* Olz = Ol + (size_t)z * sCz;
#pragma unroll
        for (int mt = 0; mt < 4; ++mt)
#pragma unroll
            for (int nt = 0; nt < 4; ++nt)
#pragma unroll
                for (int j = 0; j < 4; ++j) {
                    float v = acc[mt][nt][j];
                    u16 h = f2bf(v);
                    size_t o = (size_t)(orow0 + mt * 16 + j) * N + ocol0 + nt * 16;
                    Ohz[o] = h;
                    Olz[o] = f2bf(v - bf2f(h));
                }
    } else {
        // OMODE 2: C = Vp2 base, C2 = Kp2 base, z = b
#pragma unroll
        for (int nt = 0; nt < 4; ++nt) {
            int col = ocol0 + nt * 16;
            if (col < HHD) {
                int h = col >> 6, d = col & 63;
                float* dst = C + (((size_t)z * NH + h) * TLEN) * 64 + d;
#pragma unroll
                for (int mt = 0; mt < 4; ++mt)
#pragma unroll
                    for (int j = 0; j < 4; ++j)
                        dst[(size_t)(orow0 + mt * 16 + j) * 64] = acc[mt][nt][j];
            } else {
                int c = col - HHD;
                int k = c / HR;
                int rr = c - k * HR;
                int h = rr / RDIM;
                int r = rr - h * RDIM;
                float* dst = C2 + ((((size_t)z * NKOPS + k) * NH + h) * TLEN) * 48 + r;
#pragma unroll
                for (int mt = 0; mt < 4; ++mt)
#pragma unroll
                    for (int j = 0; j < 4; ++j)
                        dst[(size_t)(orow0 + mt * 16 + j) * 48] = acc[mt][nt][j];
            }
        }
    }
}

// ---------------- Gram (fallback): 16-way interleaved time-split partials ----------------
__global__ __launch_bounds__(256) void gram_kernel(const float* __restrict__ Kp,
                                                   const float* __restrict__ Vp,
                                                   float* __restrict__ Gpart,
                                                   float* __restrict__ Mpart,
                                                   float* __restrict__ Cpart,
                                                   const int* __restrict__ pl_ptr)
{
    int h = blockIdx.x, b = blockIdx.y, sp = blockIdx.z;
    int pl = clamp_pl(pl_ptr[0]);
    __shared__ float pks[65][48];
    __shared__ float pvs[64][64];
    int tid = threadIdx.x;
    int tx = tid & 15, ty = tid >> 4;
    float gacc[3][3] = {}, macc[3][3] = {}, cacc[4][3] = {};
    const float* Kbase = Kp + (size_t)b * TLEN * HR + h * RDIM;
    const float* Vbase = Vp + (size_t)b * TLEN * HHD + h * HDIM;
    const float4 z4 = make_float4(0.f, 0.f, 0.f, 0.f);

    for (int c0 = sp * 64; c0 < pl; c0 += GSPLIT * 64) {
        for (int idx = tid; idx < 65 * 12; idx += 256) {
            int rr = idx / 12, c4 = idx % 12;
            int tg = c0 + rr;
            *(float4*)&pks[rr][c4 * 4] =
                (tg < pl) ? *(const float4*)&Kbase[(size_t)tg * HR + c4 * 4] : z4;
        }
        for (int idx = tid; idx < 64 * 16; idx += 256) {
            int rr = idx >> 4, c4 = idx & 15;
            int tg = c0 + rr;
            *(float4*)&pvs[rr][c4 * 4] =
                (tg < pl) ? *(const float4*)&Vbase[(size_t)tg * HHD + c4 * 4] : z4;
        }
        __syncthreads();
        float cura[3], curb[3];
#pragma unroll
        for (int i = 0; i < 3; ++i) {
            cura[i] = pks[0][tx * 3 + i];
            curb[i] = pks[0][ty * 3 + i];
        }
#pragma unroll 2
        for (int l = 0; l < 64; ++l) {
            float nxta[3], nxtb[3];
#pragma unroll
            for (int i = 0; i < 3; ++i) {
                nxta[i] = pks[l + 1][tx * 3 + i];
                nxtb[i] = pks[l + 1][ty * 3 + i];
            }
            float4 v4 = *(const float4*)&pvs[l][ty * 4];
            float vv[4] = { v4.x, v4.y, v4.z, v4.w };
#pragma unroll
            for (int i = 0; i < 3; ++i)
#pragma unroll
                for (int j = 0; j < 3; ++j) {
                    gacc[i][j] += cura[i] * curb[j];
                    macc[i][j] += nxta[i] * curb[j];
                }
#pragma unroll
            for (int j = 0; j < 4; ++j)
#pragma unroll
                for (int i = 0; i < 3; ++i)
                    cacc[j][i] += vv[j] * cura[i];
#pragma unroll
            for (int i = 0; i < 3; ++i) { cura[i] = nxta[i]; curb[i] = nxtb[i]; }
        }
        __syncthreads();
    }
    size_t pbase = (size_t)sp * (BSZ * NH) + b * NH + h;
    float* Gp = Gpart + pbase * 2304;
    float* Mp = Mpart + pbase * 2304;
    float* Cp = Cpart + pbase * 3072;
#pragma unroll
    for (int i = 0; i < 3; ++i)
#pragma unroll
        for (int j = 0; j < 3; ++j) {
            Gp[(tx * 3 + i) * 48 + (ty * 3 + j)] = gacc[i][j];
            Mp[(tx * 3 + i) * 48 + (ty * 3 + j)] = macc[i][j];
        }
#pragma unroll
    for (int j = 0; j < 4; ++j)
#pragma unroll
        for (int i = 0; i < 3; ++i)
            Cp[(ty * 4 + j) * 48 + (tx * 3 + i)] = cacc[j][i];
}

// ---------------- Gram (blocked): z = k*4+sp, reads Vp2/Kp2 (contiguous) ----------------
__global__ __launch_bounds__(256) void gram_blk(const float* __restrict__ Vp2,
                                                const float* __restrict__ Kp2,
                                                float* __restrict__ Gpart,
                                                float* __restrict__ Mpart,
                                                float* __restrict__ Cpart,
                                                const int* __restrict__ pl_ptr)
{
    int h = blockIdx.x, b = blockIdx.y, zz = blockIdx.z;
    int k = zz >> 2, sp = zz & 3;
    int pl = clamp_pl(pl_ptr[0]);
    __shared__ float pks[65][48];
    __shared__ float pvs[64][64];
    int tid = threadIdx.x;
    int tx = tid & 15, ty = tid >> 4;
    float gacc[3][3] = {}, macc[3][3] = {}, cacc[4][3] = {};
    const float* Kbase = Kp2 + ((((size_t)b * NKOPS + k) * NH + h) * TLEN) * 48;
    const float* Vbase = Vp2 + (((size_t)b * NH + h) * TLEN) * 64;
    const float4 z4 = make_float4(0.f, 0.f, 0.f, 0.f);

    for (int c0 = sp * 64; c0 < pl; c0 += 4 * 64) {
        for (int idx = tid; idx < 65 * 12; idx += 256) {
            int rr = idx / 12, c4 = idx % 12;
            int tg = c0 + rr;
            *(float4*)&pks[rr][c4 * 4] =
                (tg < pl) ? *(const float4*)&Kbase[(size_t)tg * 48 + c4 * 4] : z4;
        }
        for (int idx = tid; idx < 64 * 16; idx += 256) {
            int rr = idx >> 4, c4 = idx & 15;
            int tg = c0 + rr;
            *(float4*)&pvs[rr][c4 * 4] =
                (tg < pl) ? *(const float4*)&Vbase[(size_t)tg * 64 + c4 * 4] : z4;
        }
        __syncthreads();
        float cura[3], curb[3];
#pragma unroll
        for (int i = 0; i < 3; ++i) {
            cura[i] = pks[0][tx * 3 + i];
            curb[i] = pks[0][ty * 3 + i];
        }
#pragma unroll 2
        for (int l = 0; l < 64; ++l) {
            float nxta[3], nxtb[3];
#pragma unroll
            for (int i = 0; i < 3; ++i) {
                nxta[i] = pks[l + 1][tx * 3 + i];
                nxtb[i] = pks[l + 1][ty * 3 + i];
            }
            float4 v4 = *(const float4*)&pvs[l][ty * 4];
            float vv[4] = { v4.x, v4.y, v4.z, v4.w };
#pragma unroll
            for (int i = 0; i < 3; ++i)
#pragma unroll
                for (int j = 0; j < 3; ++j) {
                    gacc[i][j] += cura[i] * curb[j];
                    macc[i][j] += nxta[i] * curb[j];
                }
#pragma unroll
            for (int j = 0; j < 4; ++j)
#pragma unroll
                for (int i = 0; i < 3; ++i)
                    cacc[j][i] += vv[j] * cura[i];
#pragma unroll
            for (int i = 0; i < 3; ++i) { cura[i] = nxta[i]; curb[i] = nxtb[i]; }
        }
        __syncthreads();
    }
    size_t pbase = (size_t)zz * (BSZ * NH) + b * NH + h;   // region zz = k*4+sp in [0,16)
    float* Gp = Gpart + pbase * 2304;
    float* Mp = Mpart + pbase * 2304;
    float* Cp = Cpart + pbase * 3072;
#pragma unroll
    for (int i = 0; i < 3; ++i)
#pragma unroll
        for (int j = 0; j < 3; ++j) {
            Gp[(tx * 3 + i) * 48 + (ty * 3 + j)] = gacc[i][j];
            Mp[(tx * 3 + i) * 48 + (ty * 3 + j)] = macc[i][j];
        }
#pragma unroll
    for (int j = 0; j < 4; ++j)
#pragma unroll
        for (int i = 0; i < 3; ++i)
            Cp[(ty * 4 + j) * 48 + (tx * 3 + i)] = cacc[j][i];
}

// fallback reduce: GSPLIT partials -> per-k slot
__global__ __launch_bounds__(256) void gram_reduce(const float* __restrict__ Gpart,
                                                   const float* __restrict__ Mpart,
                                                   const float* __restrict__ Cpart,
                                                   float* __restrict__ Gb,
                                                   float* __restrict__ Mb,
                                                   float* __restrict__ Cb,
                                                   int k)
{
    int p = blockIdx.x;               // b*NH+h
    size_t ob = ((size_t)k * (BSZ * NH) + p);
    for (int idx = threadIdx.x; idx < 2304; idx += 256) {
        float sg = 0.f, sm = 0.f;
#pragma unroll
        for (int sp = 0; sp < GSPLIT; ++sp) {
            size_t pb = ((size_t)sp * (BSZ * NH) + p);
            sg += Gpart[pb * 2304 + idx];
            sm += Mpart[pb * 2304 + idx];
        }
        Gb[ob * 2304 + idx] = sg;
        Mb[ob * 2304 + idx] = sm;
    }
    for (int idx = threadIdx.x; idx < 3072; idx += 256) {
        float sc = 0.f;
#pragma unroll
        for (int sp = 0; sp < GSPLIT; ++sp)
            sc += Cpart[((size_t)sp * (BSZ * NH) + p) * 3072 + idx];
        Cb[ob * 3072 + idx] = sc;
    }
}

// ---------------- per-(k,b,h) fused solver: F = C_v * (scl^2 * P*P*H) ----------------
// Loads G/M/Cv by summing nsum partial regions (region index k*nsum+sp, deterministic order).
__global__ __launch_bounds__(256) void solver_kernel(const float* __restrict__ Gpart,
                                                     const float* __restrict__ Mpart,
                                                     const float* __restrict__ Cpart,
                                                     int nsum,
                                                     float* __restrict__ Fb,
                                                     const float* __restrict__ log_ridges,
                                                     const float* __restrict__ log_gammas)
{
    int blk = blockIdx.x;                 // (k*BSZ + b)*NH + h
    int k = blk / (BSZ * NH);
    int p64 = blk - k * (BSZ * NH);
    int tid = threadIdx.x;
    int ti = tid >> 4, tj = tid & 15;
    int i0 = ti * 3, j0 = tj * 3;

    __shared__ float A [48 * SST];
    __shared__ float Hs[48 * SST];
    __shared__ float Mm[48 * SST];
    __shared__ float Pm[48 * SST];
    __shared__ float Pt[48 * SST];
    __shared__ float pvb[4][SST];

    size_t base = (size_t)blk;
    float ridge = expf(log_ridges[k]);

    for (int idx = tid; idx < 2304; idx += 256) {
        int i = idx / 48, j = idx % 48;
        float sg = 0.f, sm = 0.f;
        for (int sp = 0; sp < nsum; ++sp) {
            size_t pb = ((size_t)(k * nsum + sp) * (BSZ * NH) + p64);
            sg += Gpart[pb * 2304 + idx];
            sm += Mpart[pb * 2304 + idx];
        }
        A [i * SST + j] = sg + ((i == j) ? ridge : 0.f);
        Hs[i * SST + j] = (i == j) ? 1.f : 0.f;
        Mm[i * SST + j] = sm;
    }
    __syncthreads();

    for (int p = 0; p < 48; ++p) {
        int p4 = p >> 2;
        float pr = 1.0f / fmaxf(A[p * SST + p], 1e-30f);
        int c4a = p4 + 1;
        int nA4 = 11 - p4;
        int nb  = 3 - (p & 3);
        for (int q = tid; q < 576; q += 256) {
            int i = q / 12, c = q % 12;
            if (i == p) continue;
            float f = A[i * SST + p] * pr;
            if (c < nA4) {
                int c4 = c4a + c;
                float4 prw = *(const float4*)&A[p * SST + c4 * 4];
                float4* d = (float4*)&A[i * SST + c4 * 4];
                float4 v = *d;
                v.x -= f * prw.x; v.y -= f * prw.y;
                v.z -= f * prw.z; v.w -= f * prw.w;
                *d = v;
            } else {
                int c4 = c - nA4;
                float4 prw = *(const float4*)&Hs[p * SST + c4 * 4];
                float4* d = (float4*)&Hs[i * SST + c4 * 4];
                float4 v = *d;
                v.x -= f * prw.x; v.y -= f * prw.y;
                v.z -= f * prw.z; v.w -= f * prw.w;
                *d = v;
            }
        }
        if (nb) {
            for (int i = tid; i < 48; i += 256) {
                if (i == p) continue;
                float f = A[i * SST + p] * pr;
                for (int c = p + 1; c < 4 * c4a; ++c)
                    A[i * SST + c] -= f * A[p * SST + c];
            }
        }
        __syncthreads();
    }
    for (int idx = tid; idx < 2304; idx += 256) {
        int i = idx / 48, j = idx % 48;
        Hs[i * SST + j] /= fmaxf(A[i * SST + i], 1e-30f);
    }
    __syncthreads();
    for (int idx = tid; idx < 2304; idx += 256) {
        int i = idx / 48, j = idx % 48;
        A[j * SST + i] = Mm[i * SST + j];
    }
    __syncthreads();
    {
        float acc[3][3];
        mm48_3x3(Hs, A, i0, j0, acc);
#pragma unroll
        for (int r = 0; r < 3; ++r)
#pragma unroll
            for (int c = 0; c < 3; ++c) {
                Pm[(i0 + r) * SST + j0 + c] = acc[r][c];
                Pt[(j0 + c) * SST + i0 + r] = acc[r][c];
            }
    }
    __syncthreads();
    {
        float acc[3][3];
        mm48_3x3(Hs, Mm, i0, j0, acc);
        __syncthreads();
#pragma unroll
        for (int r = 0; r < 3; ++r)
#pragma unroll
            for (int c = 0; c < 3; ++c)
                A[(i0 + r) * SST + j0 + c] = acc[r][c];
    }
    __syncthreads();
    {
        float acc[3][3];
        mm48_3x3(A, Pt, i0, j0, acc);
        __syncthreads();
#pragma unroll
        for (int r = 0; r < 3; ++r)
#pragma unroll
            for (int c = 0; c < 3; ++c) {
                Mm[(i0 + r) * SST + j0 + c] = acc[r][c];
                A [(j0 + c) * SST + i0 + r] = acc[r][c];
            }
    }
    __syncthreads();
    {
        float acc[3][3];
        mm48_3x3(Mm, A, i0, j0, acc);
#pragma unroll
        for (int r = 0; r < 3; ++r)
#pragma unroll
            for (int c = 0; c < 3; ++c)
                Pt[(i0 + r) * SST + j0 + c] = acc[r][c];
    }
    __syncthreads();
    for (int idx = tid; idx < 2304; idx += 256) {
        int i = idx / 48, j = idx % 48;
        A[j * SST + i] = Pt[i * SST + j];
    }
    __syncthreads();
    {
        float acc[3][3];
        mm48_3x3(Pt, A, i0, j0, acc);
        __syncthreads();
#pragma unroll
        for (int r = 0; r < 3; ++r)
#pragma unroll
            for (int c = 0; c < 3; ++c)
                Mm[(i0 + r) * SST + j0 + c] = acc[r][c];
    }
    __syncthreads();

    int ln = tid & 63, w = tid >> 6;
    float* pv = pvb[w];
    if (ln < 48) pv[ln] = ((float)((ln * 2654435761u) & 0xFFFF)) / 65536.0f + 0.5f;
    WB();
    float lam = 0.f;
    for (int it = 0; it < 25; ++it) {
        float z = 0.f;
        if (ln < 48) z = dot48(&Mm[ln * SST], pv);
        if (it == 24) {
            float nn = z * z;
            for (int off = 1; off < 64; off <<= 1) nn += __shfl_xor(nn, off);
            lam = sqrtf(nn);
            break;
        }
        if ((it & 1) == 1) {
            float nn = z * z;
            for (int off = 1; off < 64; off <<= 1) nn += __shfl_xor(nn, off);
            z *= rsqrtf(fmaxf(nn, 1e-30f));
        }
        WB();
        if (ln < 48) pv[ln] = z;
        WB();
    }
    float sigma = sqrtf(sqrtf(sqrtf(fmaxf(lam, 0.f))));
    float gamma = expf(log_gammas[k]);
    float scl = fminf(gamma, 1.f) / fmaxf(fmaxf(sigma, 1e-8f), 1.f);
    float s2 = scl * scl;

    {
        float acc[3][3];
        mm48_3x3(Pm, Hs, i0, j0, acc);
        __syncthreads();
#pragma unroll
        for (int r = 0; r < 3; ++r)
#pragma unroll
            for (int c = 0; c < 3; ++c)
                A[(j0 + c) * SST + i0 + r] = acc[r][c];
    }
    __syncthreads();
    {
        float acc[3][3];
        mm48_3x3(Pm, A, i0, j0, acc);
        __syncthreads();
#pragma unroll
        for (int r = 0; r < 3; ++r)
#pragma unroll
            for (int c = 0; c < 3; ++c)
                Pt[(j0 + c) * SST + i0 + r] = s2 * acc[r][c];
    }
    __syncthreads();
    for (int idx = tid; idx < 3072; idx += 256) {
        int row = idx / 48, col = idx % 48;
        float sc = 0.f;
        for (int sp = 0; sp < nsum; ++sp)
            sc += Cpart[((size_t)(k * nsum + sp) * (BSZ * NH) + p64) * 3072 + idx];
        if (row < 48) Mm[row * SST + col] = sc;
        else          A [(row - 48) * SST + col] = sc;
    }
    __syncthreads();
    {
        int fi0 = ti * 4, fj0 = tj * 3;
        const float* crow0 = (fi0 < 48) ? &Mm[fi0 * SST] : &A[(fi0 - 48) * SST];
        float acc[4][3];
#pragma unroll
        for (int r = 0; r < 4; ++r)
#pragma unroll
            for (int c = 0; c < 3; ++c) acc[r][c] = 0.f;
#pragma unroll 4
        for (int m = 0; m < 12; ++m) {
            float4 a0 = *(const float4*)(crow0 + 0 * SST + m * 4);
            float4 a1 = *(const float4*)(crow0 + 1 * SST + m * 4);
            float4 a2 = *(const float4*)(crow0 + 2 * SST + m * 4);
            float4 a3 = *(const float4*)(crow0 + 3 * SST + m * 4);
            float4 b0 = *(const float4*)(&Pt[(fj0 + 0) * SST] + m * 4);
            float4 b1 = *(const float4*)(&Pt[(fj0 + 1) * SST] + m * 4);
            float4 b2 = *(const float4*)(&Pt[(fj0 + 2) * SST] + m * 4);
            acc[0][0] += a0.x*b0.x + a0.y*b0.y + a0.z*b0.z + a0.w*b0.w;
            acc[0][1] += a0.x*b1.x + a0.y*b1.y + a0.z*b1.z + a0.w*b1.w;
            acc[0][2] += a0.x*b2.x + a0.y*b2.y + a0.z*b2.z + a0.w*b2.w;
            acc[1][0] += a1.x*b0.x + a1.y*b0.y + a1.z*b0.z + a1.w*b0.w;
            acc[1][1] += a1.x*b1.x + a1.y*b1.y + a1.z*b1.z + a1.w*b1.w;
            acc[1][2] += a1.x*b2.x + a1.y*b2.y + a1.z*b2.z + a1.w*b2.w;
            acc[2][0] += a2.x*b0.x + a2.y*b0.y + a2.z*b0.z + a2.w*b0.w;
            acc[2][1] += a2.x*b1.x + a2.y*b1.y + a2.z*b1.z + a2.w*b1.w;
            acc[2][2] += a2.x*b2.x + a2.y*b2.y + a2.z*b2.z + a2.w*b2.w;
            acc[3][0] += a3.x*b0.x + a3.y*b0.y + a3.z*b0.z + a3.w*b0.w;
            acc[3][1] += a3.x*b1.x + a3.y*b1.y + a3.z*b1.z + a3.w*b1.w;
            acc[3][2] += a3.x*b2.x + a3.y*b2.y + a3.z*b2.z + a3.w*b2.w;
        }
#pragma unroll
        for (int r = 0; r < 4; ++r)
#pragma unroll
            for (int c = 0; c < 3; ++c)
                Fb[base * 3072 + (size_t)(fi0 + r) * 48 + fj0 + c] = acc[r][c];
    }
}

// ---------------- W_cmb build -> bf16 hi/lo ----------------
__global__ __launch_bounds__(256) void wcmb_kernel(const float* __restrict__ WQ,
                                                   const float* __restrict__ Fb,
                                                   const float* __restrict__ gate_alphas,
                                                   u16* __restrict__ Wh,
                                                   u16* __restrict__ Wl)
{
    int dt = blockIdx.x;
    int h = blockIdx.y, b = blockIdx.z;
    __shared__ float wq[64][49];
    __shared__ float fs[64][49];
    int tid = threadIdx.x;
    int tx = tid & 15, ty = tid >> 4;
    float acc[4][4] = {};
    for (int k = 0; k < NKOPS; ++k) {
        float gate = 1.0f / (1.0f + expf(-gate_alphas[k]));
        for (int idx = tid; idx < 64 * 48; idx += 256) {
            int rr = idx / 48, cc = idx % 48;
            wq[rr][cc] = WQ[((size_t)k * DDIM + dt * 64 + rr) * HR + h * RDIM + cc];
            fs[rr][cc] = gate * Fb[(((size_t)k * BSZ + b) * NH + h) * 3072 + idx];
        }
        __syncthreads();
        for (int r = 0; r < 48; ++r) {
            float a[4], bb[4];
#pragma unroll
            for (int i = 0; i < 4; ++i) { a[i] = wq[tx * 4 + i][r]; bb[i] = fs[ty * 4 + i][r]; }
#pragma unroll
            for (int i = 0; i < 4; ++i)
#pragma unroll
                for (int j = 0; j < 4; ++j)
                    acc[i][j] += a[i] * bb[j];
        }
        __syncthreads();
    }
#pragma unroll
    for (int i = 0; i < 4; ++i)
#pragma unroll
        for (int j = 0; j < 4; ++j) {
            size_t o = ((size_t)b * DDIM + dt * 64 + tx * 4 + i) * HHD + h * HDIM + ty * 4 + j;
            float v = acc[i][j];
            u16 hh = f2bf(v);
            Wh[o] = hh;
            Wl[o] = f2bf(v - bf2f(hh));
        }
}

// ---------------- host launch ----------------
extern "C" void kernel_launch(void* const* d_in, const int* in_sizes, int n_in,
                              void* d_out, int out_size, void* d_ws, size_t ws_size,
                              hipStream_t stream)
{
    const float* hs          = (const float*)d_in[0];
    const float* WK          = (const float*)d_in[1];
    const float* WQ          = (const float*)d_in[2];
    const float* WV          = (const float*)d_in[3];
    const float* WO          = (const float*)d_in[4];
    const float* ln_g        = (const float*)d_in[5];
    const float* ln_b        = (const float*)d_in[6];
    const float* gate_alphas = (const float*)d_in[7];
    const float* gate_alpha  = (const float*)d_in[8];
    const float* log_ridges  = (const float*)d_in[9];
    const float* log_gammas  = (const float*)d_in[10];
    const int*   pl_ptr      = (const int*)d_in[11];
    float* out = (float*)d_out;
    float* wsf = (float*)d_ws;

    // gram partials in d_out (dead before final GEMM overwrites all of d_out)
    float* GpartO = out;                     // 16*64*2304 = 2,359,296
    float* MpartO = out + 2359296;           // 2,359,296
    float* CpartO = out + 4718592;           // 3,145,728 (end 7,864,320 < 8,388,608)

    const size_t BIG_NEED = (size_t)(12582912 + 33554432) * 4;   // 184,549,376 B (proven to trigger)

    if (ws_size >= BIG_NEED) {
        // ===== batched path: one KV GEMM (N=4096) with blocked output, blocked grams =====
        u16* n_hi    = (u16*)(wsf + 0);
        u16* n_lo    = (u16*)(wsf + 4194304);
        u16* Wall_h  = (u16*)(wsf + 8388608);      // [4096][1024] bf16 hi
        u16* Wall_l  = (u16*)(wsf + 10485760);
        u16* WVt_h   = Wall_h;
        u16* WVt_l   = Wall_l;
        u16* WKt_ah  = Wall_h + (size_t)HHD * DDIM;
        u16* WKt_al  = Wall_l + (size_t)HHD * DDIM;
        float* Vp2   = wsf + 12582912;             // [4][16][2048][64]  = 8,388,608 f32
        float* Kp2   = wsf + 20971520;             // [4][4][16][2048][48] = 25,165,824 f32 (end 46,137,344)
        // aliases after grams (Vp2/Kp2 dead; disjoint, stream-ordered):
        u16* WOt_h   = (u16*)(wsf + 12582912);     // 524,288 f32
        u16* WOt_l   = (u16*)(wsf + 13107200);     // 524,288 f32
        float* Fb    = wsf + 13631488;             // 786,432
        u16* Wcmb_h  = (u16*)(wsf + 14417920);     // 2,097,152 f32 each
        u16* Wcmb_l  = (u16*)(wsf + 16515072);
        u16* Wfint_h = (u16*)(wsf + 18612224);
        u16* Wfint_l = (u16*)(wsf + 20709376);     // end 22,806,528 < 46,137,344

        ln_kernel<<<BSZ * TLEN, 256, 0, stream>>>(hs, ln_g, ln_b, n_hi, n_lo);
        transcvt<<<dim3(HHD / 32, DDIM / 32), 256, 0, stream>>>(WV, WVt_h, WVt_l, DDIM, HHD);
        transcvt_wk<<<dim3(HR / 32, DDIM / 32, NKOPS), 256, 0, stream>>>(WK, WKt_ah, WKt_al);

        // [Vp2|Kp2] = normed_prefix @ [WV | WK0..3]  (blocked output)
        gemm_mfma<2><<<dim3(NALL / 128, TLEN / 128, BSZ), 256, 0, stream>>>(
            n_hi, n_lo, (long)TLEN * DDIM, Wall_h, Wall_l, 0,
            Vp2, Kp2, nullptr, nullptr, 0,
            TLEN, NALL, DDIM, pl_ptr, nullptr);

        gram_blk<<<dim3(NH, BSZ, 16), 256, 0, stream>>>(Vp2, Kp2, GpartO, MpartO, CpartO, pl_ptr);

        transcvt<<<dim3(DDIM / 32, HHD / 32), 256, 0, stream>>>(WO, WOt_h, WOt_l, HHD, DDIM);

        solver_kernel<<<NKOPS * BSZ * NH, 256, 0, stream>>>(
            GpartO, MpartO, CpartO, 4, Fb, log_ridges, log_gammas);
        wcmb_kernel<<<dim3(DDIM / 64, NH, BSZ), 256, 0, stream>>>(WQ, Fb, gate_alphas, Wcmb_h, Wcmb_l);

        gemm_mfma<1><<<dim3(DDIM / 128, DDIM / 128, BSZ), 256, 0, stream>>>(
            WOt_h, WOt_l, 0, Wcmb_h, Wcmb_l, (long)DDIM * HHD,
            nullptr, nullptr, Wfint_h, Wfint_l, (long)DDIM * DDIM,
            DDIM, DDIM, HHD, nullptr, nullptr);

        gemm_mfma<0><<<dim3(DDIM / 128, TLEN / 128, BSZ), 256, 0, stream>>>(
            n_hi, n_lo, (long)TLEN * DDIM, Wfint_h, Wfint_l, (long)DDIM * DDIM,
            out, nullptr, nullptr, nullptr, (long)TLEN * DDIM,
            TLEN, DDIM, DDIM, nullptr, gate_alpha);
        return;
    }

    // ===== fallback path: r17 structure =====
    u16* n_hi    = (u16*)(wsf + 0);
    u16* n_lo    = (u16*)(wsf + 4194304);
    u16* WVt_h   = (u16*)(wsf + 8388608);
    u16* WVt_l   = (u16*)(wsf + 8912896);
    u16* WKt_ah  = (u16*)(wsf + 9437184);
    u16* WKt_al  = (u16*)(wsf + 11010048);
    float* Vp    = wsf + 12582912;
    float* Kp    = wsf + 20971520;
    float* Gb    = wsf + 27262976;
    float* Mb    = wsf + 27852800;
    float* Cb    = wsf + 28442624;
    u16* Wcmb_h  = (u16*)Vp;
    u16* Wcmb_l  = (u16*)(Vp + 2097152);
    u16* Wfint_h = (u16*)(Vp + 4194304);
    u16* Wfint_l = (u16*)(Vp + 6291456);
    u16* WOt_h   = (u16*)Kp;
    u16* WOt_l   = (u16*)(Kp + 524288);
    float* Fb    = Kp + 1048576;

    ln_kernel<<<BSZ * TLEN, 256, 0, stream>>>(hs, ln_g, ln_b, n_hi, n_lo);
    transcvt_wk<<<dim3(HR / 32, DDIM / 32, NKOPS), 256, 0, stream>>>(WK, WKt_ah, WKt_al);
    transcvt<<<dim3(HHD / 32, DDIM / 32), 256, 0, stream>>>(WV, WVt_h, WVt_l, DDIM, HHD);

    gemm_mfma<0><<<dim3(HHD / 128, TLEN / 128, BSZ), 256, 0, stream>>>(
        n_hi, n_lo, (long)TLEN * DDIM, WVt_h, WVt_l, 0,
        Vp, nullptr, nullptr, nullptr, (long)TLEN * HHD,
        TLEN, HHD, DDIM, pl_ptr, nullptr);

    for (int k = 0; k < NKOPS; ++k) {
        gemm_mfma<0><<<dim3(HR / 128, TLEN / 128, BSZ), 256, 0, stream>>>(
            n_hi, n_lo, (long)TLEN * DDIM,
            WKt_ah + (size_t)k * (HR * DDIM), WKt_al + (size_t)k * (HR * DDIM), 0,
            Kp, nullptr, nullptr, nullptr, (long)TLEN * HR,
            TLEN, HR, DDIM, pl_ptr, nullptr);
        gram_kernel<<<dim3(NH, BSZ, GSPLIT), 256, 0, stream>>>(Kp, Vp, GpartO, MpartO, CpartO, pl_ptr);
        gram_reduce<<<BSZ * NH, 256, 0, stream>>>(GpartO, MpartO, CpartO, Gb, Mb, Cb, k);
    }

    transcvt<<<dim3(DDIM / 32, HHD / 32), 256, 0, stream>>>(WO, WOt_h, WOt_l, HHD, DDIM);

    solver_kernel<<<NKOPS * BSZ * NH, 256, 0, stream>>>(Gb, Mb, Cb, 1, Fb, log_ridges, log_gammas);
    wcmb_kernel<<<dim3(DDIM / 64, NH, BSZ), 256, 0, stream>>>(WQ, Fb, gate_alphas, Wcmb_h, Wcmb_l);

    gemm_mfma<1><<<dim3(DDIM / 128, DDIM / 128, BSZ), 256, 0, stream>>>(
        WOt_h, WOt_l, 0, Wcmb_h, Wcmb_l, (long)DDIM * HHD,
        nullptr, nullptr, Wfint_h, Wfint_l, (long)DDIM * DDIM,
        DDIM, DDIM, HHD, nullptr, nullptr);

    gemm_mfma<0><<<dim3(DDIM / 128, TLEN / 128, BSZ), 256, 0, stream>>>(
        n_hi, n_lo, (long)TLEN * DDIM, Wfint_h, Wfint_l, (long)DDIM * DDIM,
        out, nullptr, nullptr, nullptr, (long)TLEN * DDIM,
        TLEN, DDIM, DDIM, nullptr, gate_alpha);
}